// Round 3
// baseline (657.203 us; speedup 1.0000x reference)
//
#include <hip/hip_runtime.h>
#include <hip/hip_bf16.h>

// bf16-MFMA scaled dot-product attention with materialized attn. Round 3:
//  - V B-frags loaded directly from global (L2-resident), no LDS staging
//  - one-barrier softmax (local max+sumexp combined cross-wave analytically)
//  - LDS ~34 KB -> 4 WG/CU (16 waves/CU)
// B=64, TQ=TK=1024, DK=DV=64.
// WG = 256 thr = 4 waves; 16 queries per WG; wave w owns keys [w*256, w*256+256).

#define B_   64
#define TQ_  1024
#define TK_  1024
#define DD   64

typedef short short8 __attribute__((ext_vector_type(8)));
typedef float f32x4 __attribute__((ext_vector_type(4)));

#define PSTR 264            // shorts per P row: 16B-aligned rows
#define PWAVE (16 * PSTR)   // 4224 shorts = 8448 B per wave; 4 waves = 33792 B

__device__ __forceinline__ unsigned cvt2(float a, float b) {
    __hip_bfloat162 h = __float22bfloat162_rn(make_float2(a, b));
    unsigned u; __builtin_memcpy(&u, &h, 4); return u;
}
__device__ __forceinline__ short cvt1(float a) {
    __hip_bfloat16 h = __float2bfloat16(a);
    short s; __builtin_memcpy(&s, &h, 2); return s;
}

union Frag { short8 s; unsigned u[4]; };

__global__ __launch_bounds__(256, 4) void attn_mfma_kernel(
    const float* __restrict__ qg, const float* __restrict__ kg,
    const float* __restrict__ vg, const int* __restrict__ maskg,
    float* __restrict__ outg, float* __restrict__ attng)
{
    __shared__ __align__(16) short p_lds[4 * PWAVE];
    __shared__ float redm[4][16];
    __shared__ float reds[4][16];

    const int t    = threadIdx.x;
    const int wave = t >> 6, lane = t & 63;
    const int quad = lane >> 4, n16 = lane & 15;
    const int b    = blockIdx.y;
    const int q0   = blockIdx.x * 16;
    const int kbase = wave * 256;

    short* pw = p_lds + wave * PWAVE;

    // ---- Q A-frags: lane n16 holds Q[q0+n16][f*32 + quad*8 + j] ----
    Frag aq[2];
    {
        const float* qp = qg + ((size_t)(b * TQ_ + q0 + n16)) * DD + quad * 8;
        #pragma unroll
        for (int f = 0; f < 2; ++f) {
            float4 x = *(const float4*)(qp + f * 32);
            float4 y = *(const float4*)(qp + f * 32 + 4);
            aq[f].u[0] = cvt2(x.x, x.y); aq[f].u[1] = cvt2(x.z, x.w);
            aq[f].u[2] = cvt2(y.x, y.y); aq[f].u[3] = cvt2(y.z, y.w);
        }
    }

    float s_reg[64];   // s_reg[kt*4+r]: row quad*4+r, key kbase + kt*16 + n16

    // ================= S = Q K^T * 0.125 + mask =================
    const float* kbp = kg + (size_t)b * TK_ * DD;
    const int*   mbp = maskg + ((size_t)(b * TQ_ + q0 + quad * 4)) * TK_ + kbase + n16;
    #pragma unroll
    for (int kt = 0; kt < 16; ++kt) {
        const float* kp = kbp + (size_t)(kbase + kt * 16 + n16) * DD + quad * 8;
        Frag bk[2];
        #pragma unroll
        for (int f = 0; f < 2; ++f) {
            float4 x = *(const float4*)(kp + f * 32);
            float4 y = *(const float4*)(kp + f * 32 + 4);
            bk[f].u[0] = cvt2(x.x, x.y); bk[f].u[1] = cvt2(x.z, x.w);
            bk[f].u[2] = cvt2(y.x, y.y); bk[f].u[3] = cvt2(y.z, y.w);
        }
        f32x4 acc = {0.f, 0.f, 0.f, 0.f};
        acc = __builtin_amdgcn_mfma_f32_16x16x32_bf16(aq[0].s, bk[0].s, acc, 0, 0, 0);
        acc = __builtin_amdgcn_mfma_f32_16x16x32_bf16(aq[1].s, bk[1].s, acc, 0, 0, 0);
        #pragma unroll
        for (int r = 0; r < 4; ++r) {
            const int m = mbp[(size_t)r * TK_ + kt * 16];
            s_reg[kt * 4 + r] = acc[r] * 0.125f + (m ? 0.f : -1e9f);
        }
    }

    // ================= one-barrier softmax =================
    float lmax[4], lsum[4];
    #pragma unroll
    for (int r = 0; r < 4; ++r) {
        float m = s_reg[r];
        #pragma unroll
        for (int kt = 1; kt < 16; ++kt) m = fmaxf(m, s_reg[kt * 4 + r]);
        #pragma unroll
        for (int off = 8; off > 0; off >>= 1) m = fmaxf(m, __shfl_xor(m, off));
        lmax[r] = m;
    }
    #pragma unroll
    for (int r = 0; r < 4; ++r) lsum[r] = 0.f;
    #pragma unroll
    for (int kt = 0; kt < 16; ++kt) {
        #pragma unroll
        for (int r = 0; r < 4; ++r) {
            const float p = __expf(s_reg[kt * 4 + r] - lmax[r]);
            s_reg[kt * 4 + r] = p;         // exp(s - lmax), local
            lsum[r] += p;
        }
    }
    #pragma unroll
    for (int r = 0; r < 4; ++r) {
        #pragma unroll
        for (int off = 8; off > 0; off >>= 1) lsum[r] += __shfl_xor(lsum[r], off);
    }
    if (n16 == 0) {
        #pragma unroll
        for (int r = 0; r < 4; ++r) {
            redm[wave][quad * 4 + r] = lmax[r];
            reds[wave][quad * 4 + r] = lsum[r];
        }
    }
    __syncthreads();
    float fscale[4];   // exp(lmax - gmax) / gsum
    #pragma unroll
    for (int r = 0; r < 4; ++r) {
        const int row = quad * 4 + r;
        const float m0 = redm[0][row], m1 = redm[1][row];
        const float m2 = redm[2][row], m3 = redm[3][row];
        const float gmax = fmaxf(fmaxf(m0, m1), fmaxf(m2, m3));
        const float gsum = reds[0][row] * __expf(m0 - gmax)
                         + reds[1][row] * __expf(m1 - gmax)
                         + reds[2][row] * __expf(m2 - gmax)
                         + reds[3][row] * __expf(m3 - gmax);
        fscale[r] = __expf(lmax[r] - gmax) / gsum;
    }

    // ---- normalize; write attn (fp32) and P (bf16 -> wave-private LDS) ----
    float* abp = attng + ((size_t)(b * TQ_ + q0 + quad * 4)) * TK_ + kbase + n16;
    #pragma unroll
    for (int kt = 0; kt < 16; ++kt) {
        #pragma unroll
        for (int r = 0; r < 4; ++r) {
            const float pv = s_reg[kt * 4 + r] * fscale[r];
            abp[(size_t)r * TK_ + kt * 16] = pv;
            pw[(quad * 4 + r) * PSTR + kt * 16 + n16] = cvt1(pv);
        }
    }

    // ================= O = P V  (V B-frags direct from global) =================
    f32x4 oacc[4];
    #pragma unroll
    for (int dg = 0; dg < 4; ++dg) oacc[dg] = (f32x4){0.f, 0.f, 0.f, 0.f};

    const float* vbp = vg + (size_t)b * TK_ * DD;
    #pragma unroll
    for (int c = 0; c < 8; ++c) {
        const int k0 = kbase + c * 32 + quad * 8;
        Frag pf;
        pf.s = *(const short8*)(pw + n16 * PSTR + c * 32 + quad * 8);
        #pragma unroll
        for (int dg = 0; dg < 4; ++dg) {
            const float* vp = vbp + (size_t)k0 * DD + dg * 16 + n16;
            float e[8];
            #pragma unroll
            for (int j = 0; j < 8; ++j) e[j] = vp[j * DD];
            Frag vf;
            vf.u[0] = cvt2(e[0], e[1]); vf.u[1] = cvt2(e[2], e[3]);
            vf.u[2] = cvt2(e[4], e[5]); vf.u[3] = cvt2(e[6], e[7]);
            oacc[dg] = __builtin_amdgcn_mfma_f32_16x16x32_bf16(pf.s, vf.s, oacc[dg], 0, 0, 0);
        }
    }

    // ---- cross-wave O reduction (stage into own p region: 16x68 fp32) ----
    float* ow = (float*)pw;
    #pragma unroll
    for (int dg = 0; dg < 4; ++dg) {
        #pragma unroll
        for (int r = 0; r < 4; ++r)
            ow[(quad * 4 + r) * 68 + dg * 16 + n16] = oacc[dg][r];
    }
    __syncthreads();
    {
        const int row = t >> 4;
        const int col = (t & 15) * 4;
        const float* p0 = (const float*)p_lds;
        float4 o = make_float4(0.f, 0.f, 0.f, 0.f);
        #pragma unroll
        for (int w = 0; w < 4; ++w) {
            const float4 x = *(const float4*)(p0 + w * (PWAVE / 2) + row * 68 + col);
            o.x += x.x; o.y += x.y; o.z += x.z; o.w += x.w;
        }
        *(float4*)(outg + ((size_t)(b * TQ_ + q0 + row)) * DD + col) = o;
    }
}

extern "C" void kernel_launch(void* const* d_in, const int* in_sizes, int n_in,
                              void* d_out, int out_size, void* d_ws, size_t ws_size,
                              hipStream_t stream) {
    const float* q    = (const float*)d_in[0];
    const float* k    = (const float*)d_in[1];
    const float* v    = (const float*)d_in[2];
    const int*   mask = (const int*)d_in[3];

    float* out  = (float*)d_out;                   // [64][1024][64]
    float* attn = out + (size_t)B_ * TQ_ * DD;     // [64][1024][1024]

    dim3 grid(TQ_ / 16, B_);
    attn_mfma_kernel<<<grid, 256, 0, stream>>>(q, k, v, mask, out, attn);
}